// Round 4
// baseline (200.200 us; speedup 1.0000x reference)
//
#include <hip/hip_runtime.h>
#include <math.h>

#define DN  768
#define NC  53
#define NCP 64          // classes padded to 64 for MFMA tiles
#define MBLK 128        // rows per block in gemm_y
#define KC   128        // k-chunk (f32 elements)

typedef __attribute__((ext_vector_type(8))) __bf16 bf16x8;
typedef __attribute__((ext_vector_type(8))) short short8v;
typedef __attribute__((ext_vector_type(4))) float f32x4;
typedef __attribute__((ext_vector_type(4))) unsigned short ushort4v;

// f32 -> bf16 bits, round-to-nearest-even
static __device__ __forceinline__ unsigned short f2bf(float f) {
    unsigned int u = __builtin_bit_cast(unsigned int, f);
    u = (u + 0x7FFFu + ((u >> 16) & 1u)) >> 16;
    return (unsigned short)u;
}
static __device__ __forceinline__ float bf2f(unsigned short h) {
    unsigned int u = ((unsigned int)h) << 16;
    return __builtin_bit_cast(float, u);
}

// ---- k0: W -> Wh + Wl (bf16 split), zero-padded to 64 rows -----------------
__global__ void prep_w(const float* __restrict__ w,
                       unsigned short* __restrict__ wh,
                       unsigned short* __restrict__ wl) {
    int i = blockIdx.x * 256 + threadIdx.x;      // i = row*DN + col
    if (i >= NCP * DN) return;
    int row = i / DN;
    float v = (row < NC) ? w[i] : 0.f;
    unsigned short h = f2bf(v);
    wh[i] = h;
    wl[i] = f2bf(v - bf2f(h));
}

// ---- offs[b] = lower_bound(seg, b), b in [0, B] ----------------------------
__global__ void offs_kernel(const int* __restrict__ seg, int* __restrict__ offs,
                            int N, int B) {
    int i = blockIdx.x * blockDim.x + threadIdx.x;
    if (i >= N) return;
    int cur  = seg[i];
    int prev = (i == 0) ? -1 : seg[i - 1];
    for (int b = prev + 1; b <= cur; ++b) offs[b] = i;
    if (i == N - 1)
        for (int b = cur + 1; b <= B; ++b) offs[b] = N;
}

// ---- k1: Y[N][64] = bf16(X) @ (Wh+Wl)^T -----------------------------------
// 4 waves/block; block M-tile = 128 rows (32/wave); reg-staged swizzled LDS.
__global__ __launch_bounds__(256, 4) void gemm_y(
    const float* __restrict__ x,
    const unsigned short* __restrict__ wh,
    const unsigned short* __restrict__ wl,
    float* __restrict__ y)
{
    __shared__ unsigned short xs[MBLK * KC];     // 32 KB bf16 tile, XOR-swizzled
    char* xsb = (char*)xs;

    const int tid  = threadIdx.x;
    const int lane = tid & 63;
    const int wv   = tid >> 6;
    const int r16  = lane & 15;
    const int kgB  = (lane >> 4) * 16;           // byte offset of lane's 8-elem k-group
    const long row0 = (long)blockIdx.x * MBLK;

    f32x4 acc[2][4];
    #pragma unroll
    for (int f = 0; f < 2; ++f)
        #pragma unroll
        for (int ct = 0; ct < 4; ++ct)
            acc[f][ct] = (f32x4){0.f, 0.f, 0.f, 0.f};

    const int srow = wv * 32 + (lane >> 5);      // staging: +2*i covers 32 rows/wave
    const int sf4  = lane & 31;                  // float4 index within 512B row-chunk

    for (int ch = 0; ch < DN / KC; ++ch) {
        // ---- stage x chunk: coalesced f32 load -> bf16 -> swizzled LDS ----
        #pragma unroll
        for (int i = 0; i < 16; ++i) {
            const int row = srow + 2 * i;
            const float4 v = *(const float4*)(x + (row0 + row) * DN + ch * KC + sf4 * 4);
            ushort4v h;
            h[0] = f2bf(v.x); h[1] = f2bf(v.y); h[2] = f2bf(v.z); h[3] = f2bf(v.w);
            *(ushort4v*)(xsb + row * 256 + ((sf4 * 8) ^ ((row & 15) << 4))) = h;
        }
        __syncthreads();

        // ---- compute: 4 k-steps of 32 ----
        #pragma unroll
        for (int ks = 0; ks < 4; ++ks) {
            short8v a8[2];
            #pragma unroll
            for (int f = 0; f < 2; ++f) {
                const int arow = wv * 32 + f * 16 + r16;          // arow&15 == r16
                a8[f] = *(const short8v*)(xsb + arow * 256 + ((ks * 64 + kgB) ^ (r16 << 4)));
            }
            #pragma unroll
            for (int ct = 0; ct < 4; ++ct) {
                const size_t wo = (size_t)(ct * 16 + r16) * DN + ch * KC + ks * 32 + (lane >> 4) * 8;
                const short8v bh = *(const short8v*)(wh + wo);
                const short8v bl = *(const short8v*)(wl + wo);
                #pragma unroll
                for (int f = 0; f < 2; ++f) {
                    acc[f][ct] = __builtin_amdgcn_mfma_f32_16x16x32_bf16(
                        __builtin_bit_cast(bf16x8, a8[f]), __builtin_bit_cast(bf16x8, bh),
                        acc[f][ct], 0, 0, 0);
                    acc[f][ct] = __builtin_amdgcn_mfma_f32_16x16x32_bf16(
                        __builtin_bit_cast(bf16x8, a8[f]), __builtin_bit_cast(bf16x8, bl),
                        acc[f][ct], 0, 0, 0);
                }
            }
        }
        __syncthreads();
    }

    // ---- epilogue: C/D col = lane&15, row = (lane>>4)*4 + r ----
    #pragma unroll
    for (int f = 0; f < 2; ++f)
        #pragma unroll
        for (int ct = 0; ct < 4; ++ct) {
            const long row = row0 + wv * 32 + f * 16 + (lane >> 4) * 4;
            const int  col = ct * 16 + r16;
            #pragma unroll
            for (int r = 0; r < 4; ++r)
                y[(row + r) * NCP + col] = acc[f][ct][r];
        }
}

// ---- k2: per-bag softmax pooling over Y, lane-parallel ---------------------
__global__ __launch_bounds__(256) void pool_kernel(
    const float* __restrict__ y,
    const int*   __restrict__ label,
    const int*   __restrict__ offs,
    const float* __restrict__ bias,
    float*       __restrict__ out,
    int Btot)
{
    __shared__ float s_e[4][64];
    const int wv   = threadIdx.x >> 6;
    const int lane = threadIdx.x & 63;
    const int bag  = blockIdx.x * 4 + wv;
    if (bag >= Btot) return;
    const int s = offs[bag], e = offs[bag + 1];

    float m = -INFINITY, den = 0.f, facc = 0.f;
    for (int j0 = s; j0 < e; j0 += 64) {
        const int j = j0 + lane;
        float a = -INFINITY;
        if (j < e) a = y[(size_t)j * NCP + label[j]];   // lane-parallel gather
        float cm = a;
        #pragma unroll
        for (int off = 1; off < 64; off <<= 1) cm = fmaxf(cm, __shfl_xor(cm, off));
        const float nm = fmaxf(m, cm);
        const float sc = __expf(m - nm);                 // first iter: exp(-inf)=0
        const float ej = __expf(a - nm);                 // invalid lanes -> 0
        float cd = ej;
        #pragma unroll
        for (int off = 1; off < 64; off <<= 1) cd += __shfl_xor(cd, off);
        den = den * sc + cd;
        facc *= sc;
        s_e[wv][lane] = ej;                              // same-wave LDS, waitcnt-ordered
        const int cnt = min(64, e - j0);
        for (int t = 0; t < cnt; ++t)
            facc += s_e[wv][t] * y[(size_t)(j0 + t) * NCP + lane];  // coalesced 256B rows
        m = nm;
    }
    if (lane < NC) {
        const float inv = (den == 0.f) ? 0.f : 1.f / den;   // empty bag -> bias
        out[(size_t)bag * NC + lane] = facc * inv + bias[lane];
    }
}

extern "C" void kernel_launch(void* const* d_in, const int* in_sizes, int n_in,
                              void* d_out, int out_size, void* d_ws, size_t ws_size,
                              hipStream_t stream)
{
    const float* x     = (const float*)d_in[0];
    const int*   label = (const int*)  d_in[1];
    const int*   seg   = (const int*)  d_in[2];
    const float* w     = (const float*)d_in[3];
    const float* bias  = (const float*)d_in[4];
    float*       out   = (float*)d_out;

    const int N = in_sizes[0] / DN;     // 131072
    const int B = out_size / NC;        // 16384

    // ws layout
    unsigned short* wh   = (unsigned short*)d_ws;                    //   96 KB
    unsigned short* wl   = (unsigned short*)((char*)d_ws + 131072);  //   96 KB
    int*            offs = (int*)((char*)d_ws + 262144);             //   64 KB
    float*          y    = (float*)((char*)d_ws + 1048576);          // 33.5 MB

    hipLaunchKernelGGL(prep_w, dim3((NCP * DN + 255) / 256), dim3(256), 0, stream,
                       w, wh, wl);
    hipLaunchKernelGGL(offs_kernel, dim3((N + 255) / 256), dim3(256), 0, stream,
                       seg, offs, N, B);
    hipLaunchKernelGGL(gemm_y, dim3(N / MBLK), dim3(256), 0, stream,
                       x, wh, wl, y);
    hipLaunchKernelGGL(pool_kernel, dim3((B + 3) / 4), dim3(256), 0, stream,
                       y, label, offs, bias, out, B);
}

// Round 5
// 198.580 us; speedup vs baseline: 1.0082x; 1.0082x over previous
//
#include <hip/hip_runtime.h>
#include <math.h>

#define DN   768
#define NC   53
#define NCP  64        // classes padded for MFMA
#define BPB  16        // bags per block
#define RB   64        // rows per chunk
#define KC   128       // k per chunk
#define NKC  (DN / KC) // 6
#define YS   66        // y-tile row stride (floats), conflict-free epilogue

typedef __attribute__((ext_vector_type(8))) __bf16 bf16x8;
typedef __attribute__((ext_vector_type(8))) short short8v;
typedef __attribute__((ext_vector_type(4))) float f32x4;
typedef __attribute__((ext_vector_type(4))) unsigned short ushort4v;

// f32 -> bf16 bits, round-to-nearest-even
static __device__ __forceinline__ unsigned short f2bf(float f) {
    unsigned int u = __builtin_bit_cast(unsigned int, f);
    u = (u + 0x7FFFu + ((u >> 16) & 1u)) >> 16;
    return (unsigned short)u;
}
static __device__ __forceinline__ float bf2f(unsigned short h) {
    unsigned int u = ((unsigned int)h) << 16;
    return __builtin_bit_cast(float, u);
}

// ---- k0: W -> Wh + Wl (bf16 split), zero-padded to 64 rows -----------------
__global__ void prep_w(const float* __restrict__ w,
                       unsigned short* __restrict__ wh,
                       unsigned short* __restrict__ wl) {
    int i = blockIdx.x * 256 + threadIdx.x;
    if (i >= NCP * DN) return;
    int row = i / DN;
    float v = (row < NC) ? w[i] : 0.f;
    unsigned short h = f2bf(v);
    wh[i] = h;
    wl[i] = f2bf(v - bf2f(h));
}

// ---- offs[b] = lower_bound(seg, b), b in [0, B] ----------------------------
__global__ void offs_kernel(const int* __restrict__ seg, int* __restrict__ offs,
                            int N, int B) {
    int i = blockIdx.x * blockDim.x + threadIdx.x;
    if (i >= N) return;
    int cur  = seg[i];
    int prev = (i == 0) ? -1 : seg[i - 1];
    for (int b = prev + 1; b <= cur; ++b) offs[b] = i;
    if (i == N - 1)
        for (int b = cur + 1; b <= B; ++b) offs[b] = N;
}

// ---- fused: stream x -> Y-tile in LDS -> online softmax-pool -> logits ------
// block = 16 consecutive bags (contiguous rows). 4 waves; wave = 16-class
// column slice of the 64-row Y tile; wave also owns 4 bags' softmax state.
__global__ __launch_bounds__(256, 4) void fused_kernel(
    const float* __restrict__ x,
    const int*   __restrict__ label,
    const unsigned short* __restrict__ wh,
    const unsigned short* __restrict__ wl,
    const float* __restrict__ bias,
    const int*   __restrict__ offs,
    float*       __restrict__ out,
    int N, int Btot)
{
    __shared__ unsigned short xs[RB * KC];   // 16 KB bf16, XOR-swizzled
    __shared__ float yt[RB * YS];            // 16.9 KB
    __shared__ float se[4][64];              // per-wave e-broadcast

    const int tid  = threadIdx.x;
    const int lane = tid & 63;
    const int wv   = tid >> 6;
    const int r16  = lane & 15;
    const int kg   = lane >> 4;              // 0..3
    char* xsb = (char*)xs;

    const int b0   = blockIdx.x * BPB;
    const int bEnd = (b0 + BPB < Btot) ? b0 + BPB : Btot;
    const int r0 = offs[b0];
    const int r1 = offs[bEnd];

    float bm[4], bden[4], bfac[4];
    #pragma unroll
    for (int s = 0; s < 4; ++s) { bm[s] = -INFINITY; bden[s] = 0.f; bfac[s] = 0.f; }

    const int srow = wv * 16 + (lane >> 5);  // staging row (+2*i), 16 rows/wave
    const int sc4  = lane & 31;              // float4 idx in 512B row-slice

    for (int cr = r0; cr < r1; cr += RB) {
        f32x4 acc[4];
        #pragma unroll
        for (int f = 0; f < 4; ++f) acc[f] = (f32x4){0.f, 0.f, 0.f, 0.f};

        float4 ld[8];
        // prologue: issue chunk-0 loads (coalesced: 2 rows x 512B per instr)
        #pragma unroll
        for (int i = 0; i < 8; ++i) {
            int rl = srow + 2 * i;
            long rg = (long)cr + rl; if (rg > N - 1) rg = N - 1;   // tail clamp
            ld[i] = *(const float4*)(x + rg * (long)DN + sc4 * 4);
        }

        for (int kc = 0; kc < NKC; ++kc) {
            // convert + swizzled LDS write (consistent: pos = row*256 + (2k ^ ((row&7)<<4)))
            #pragma unroll
            for (int i = 0; i < 8; ++i) {
                int rl = srow + 2 * i;
                ushort4v h;
                h[0] = f2bf(ld[i].x); h[1] = f2bf(ld[i].y);
                h[2] = f2bf(ld[i].z); h[3] = f2bf(ld[i].w);
                *(ushort4v*)(xsb + rl * 256 + ((sc4 * 8) ^ ((rl & 7) << 4))) = h;
            }
            __syncthreads();                                    // tile ready
            if (kc + 1 < NKC) {                                 // T14: issue next early
                #pragma unroll
                for (int i = 0; i < 8; ++i) {
                    int rl = srow + 2 * i;
                    long rg = (long)cr + rl; if (rg > N - 1) rg = N - 1;
                    ld[i] = *(const float4*)(x + rg * (long)DN + (kc + 1) * KC + sc4 * 4);
                }
            }
            // compute: 4 k-steps; wave wv = classes wv*16..+15, all 64 rows
            #pragma unroll
            for (int ks = 0; ks < 4; ++ks) {
                const size_t wo = (size_t)(wv * 16 + r16) * DN + kc * KC + ks * 32 + kg * 8;
                const short8v bh = *(const short8v*)(wh + wo);
                const short8v bl = *(const short8v*)(wl + wo);
                #pragma unroll
                for (int f = 0; f < 4; ++f) {
                    const int arow = f * 16 + r16;               // arow&7 == r16&7
                    const short8v a8 = *(const short8v*)(
                        xsb + arow * 256 + ((ks * 64 + kg * 16) ^ ((r16 & 7) << 4)));
                    acc[f] = __builtin_amdgcn_mfma_f32_16x16x32_bf16(
                        __builtin_bit_cast(bf16x8, a8), __builtin_bit_cast(bf16x8, bh),
                        acc[f], 0, 0, 0);
                    acc[f] = __builtin_amdgcn_mfma_f32_16x16x32_bf16(
                        __builtin_bit_cast(bf16x8, a8), __builtin_bit_cast(bf16x8, bl),
                        acc[f], 0, 0, 0);
                }
            }
            __syncthreads();                                    // tile consumed
        }

        // acc -> y tile. C/D: col = lane&15 (class), row = kg*4 + r
        #pragma unroll
        for (int f = 0; f < 4; ++f)
            #pragma unroll
            for (int r = 0; r < 4; ++r)
                yt[(f * 16 + kg * 4 + r) * YS + wv * 16 + r16] = acc[f][r];
        __syncthreads();

        // online softmax-pool update: wave wv owns bags b0+wv*4 .. +4
        #pragma unroll
        for (int s = 0; s < 4; ++s) {
            const int bag = b0 + wv * 4 + s;
            if (bag >= bEnd) continue;
            int lo = offs[bag], hi = offs[bag + 1];
            lo = lo > cr ? lo : cr;
            hi = hi < cr + RB ? hi : cr + RB;
            const int cnt = hi - lo;                 // <= RB structurally
            if (cnt <= 0) continue;                  // wave-uniform
            float att = -INFINITY;
            if (lane < cnt) {
                const int lab = label[lo + lane];    // coalesced
                att = yt[(lo + lane - cr) * YS + lab];
            }
            float cm = att;
            #pragma unroll
            for (int off = 1; off < 64; off <<= 1) cm = fmaxf(cm, __shfl_xor(cm, off));
            const float nm  = fmaxf(bm[s], cm);
            const float scv = __expf(bm[s] - nm);    // first update: exp(-inf)=0
            const float e   = (lane < cnt) ? __expf(att - nm) : 0.f;
            float cd = e;
            #pragma unroll
            for (int off = 1; off < 64; off <<= 1) cd += __shfl_xor(cd, off);
            bden[s] = bden[s] * scv + cd;
            se[wv][lane] = e;                        // same-wave LDS broadcast
            float fa = bfac[s] * scv;
            for (int t = 0; t < cnt; ++t)
                fa += se[wv][t] * yt[(lo + t - cr) * YS + lane];  // 2-way banks: free
            bfac[s] = fa;
            bm[s] = nm;
        }
        // no barrier needed: next rc's xs/yt writes are fenced by the kc-loop barriers
    }

    // epilogue: logits = facc/den + bias
    #pragma unroll
    for (int s = 0; s < 4; ++s) {
        const int bag = b0 + wv * 4 + s;
        if (bag < bEnd && lane < NC) {
            const float inv = (bden[s] == 0.f) ? 0.f : 1.f / bden[s];  // empty bag -> bias
            out[(size_t)bag * NC + lane] = bfac[s] * inv + bias[lane];
        }
    }
}

extern "C" void kernel_launch(void* const* d_in, const int* in_sizes, int n_in,
                              void* d_out, int out_size, void* d_ws, size_t ws_size,
                              hipStream_t stream)
{
    const float* x     = (const float*)d_in[0];
    const int*   label = (const int*)  d_in[1];
    const int*   seg   = (const int*)  d_in[2];
    const float* w     = (const float*)d_in[3];
    const float* bias  = (const float*)d_in[4];
    float*       out   = (float*)d_out;

    const int N = in_sizes[0] / DN;     // 131072
    const int B = out_size / NC;        // 16384

    unsigned short* wh   = (unsigned short*)d_ws;                    // 96 KB
    unsigned short* wl   = (unsigned short*)((char*)d_ws + 131072);  // 96 KB
    int*            offs = (int*)((char*)d_ws + 262144);             // 64 KB

    hipLaunchKernelGGL(prep_w, dim3((NCP * DN + 255) / 256), dim3(256), 0, stream,
                       w, wh, wl);
    hipLaunchKernelGGL(offs_kernel, dim3((N + 255) / 256), dim3(256), 0, stream,
                       seg, offs, N, B);
    hipLaunchKernelGGL(fused_kernel, dim3((B + BPB - 1) / BPB), dim3(256), 0, stream,
                       x, label, wh, wl, bias, offs, out, N, B);
}